// Round 1
// baseline (108.173 us; speedup 1.0000x reference)
//
#include <hip/hip_runtime.h>

typedef __bf16 v8bf __attribute__((ext_vector_type(8)));
typedef float v4f __attribute__((ext_vector_type(4)));

static constexpr int NR = 8192;
static constexpr int DD = 256;
static constexpr float INV_T = 1.0f / 0.3f;

// workspace layout (bytes)
static constexpr size_t FBF_OFF = 0;                    // 8192*256*2 = 4 MiB (bf16 normalized f)
static constexpr size_t SE_OFF  = 4194304;              // 8192 f32 (sum of exp per row)
static constexpr size_t G_OFF   = SE_OFF + 8192 * 4;    // 10*256 f32 class sums
static constexpr size_t CNT_OFF = G_OFF + 2560 * 4;     // 16 i32 class counts

__global__ __launch_bounds__(256) void k_zero(float* se, float* g, int* cnt, float* out) {
    const int i = blockIdx.x * 256 + threadIdx.x;
    for (int idx = i; idx < 8192; idx += gridDim.x * 256) se[idx] = 0.f;
    for (int idx = i; idx < 2560; idx += gridDim.x * 256) g[idx] = 0.f;
    if (i < 16) cnt[i] = 0;
    if (i == 0) out[0] = 0.f;
}

// L2-normalize rows -> bf16, accumulate class sums g[10][256] and counts.
__global__ __launch_bounds__(256) void k_norm(const float* __restrict__ x,
                                              const int* __restrict__ lab,
                                              unsigned short* __restrict__ fbf,
                                              float* __restrict__ g,
                                              int* __restrict__ cnt) {
    __shared__ float gsh[2560];
    __shared__ int csh[16];
    const int tid = threadIdx.x;
    const int w = tid >> 6, l = tid & 63;
    for (int i = tid; i < 2560; i += 256) gsh[i] = 0.f;
    if (tid < 16) csh[tid] = 0;
    __syncthreads();
    #pragma unroll
    for (int it = 0; it < 8; ++it) {
        const int row = blockIdx.x * 32 + it * 4 + w;
        const float4 v = *reinterpret_cast<const float4*>(x + row * DD + l * 4);
        float ss = v.x * v.x + v.y * v.y + v.z * v.z + v.w * v.w;
        #pragma unroll
        for (int m = 1; m < 64; m <<= 1) ss += __shfl_xor(ss, m, 64);
        const float rn = 1.0f / fmaxf(sqrtf(ss), 1e-12f);
        const float f0 = v.x * rn, f1 = v.y * rn, f2 = v.z * rn, f3 = v.w * rn;
        union { __bf16 h[4]; uint2 u; } pk;
        pk.h[0] = (__bf16)f0; pk.h[1] = (__bf16)f1;
        pk.h[2] = (__bf16)f2; pk.h[3] = (__bf16)f3;
        *reinterpret_cast<uint2*>(fbf + row * DD + l * 4) = pk.u;
        const int lb = lab[row];
        float* gb = &gsh[lb * DD + l * 4];
        atomicAdd(gb + 0, f0); atomicAdd(gb + 1, f1);
        atomicAdd(gb + 2, f2); atomicAdd(gb + 3, f3);
        if (l == 0) atomicAdd(&csh[lb], 1);
    }
    __syncthreads();
    for (int i = tid; i < 2560; i += 256) atomicAdd(&g[i], gsh[i]);
    if (tid < 10) atomicAdd(&cnt[tid], csh[tid]);
}

// Gram + exp row-sum kernel. Grid 512 = 32 row-blocks x 16 col-chunks.
// Block: 4 waves x 64 rows = 256 rows; col chunk = 512, staged 32 cols (16 KiB) at a time.
__global__ __launch_bounds__(256, 2) void k_score(const unsigned short* __restrict__ fbf,
                                                  float* __restrict__ sumexp) {
    __shared__ unsigned short Bsh[2][32 * 256];   // 2 x 16 KiB, double buffered
    const int tid = threadIdx.x;
    const int w = tid >> 6, l = tid & 63;
    const int ll = l & 15, lh = l >> 4;
    const int rb = blockIdx.x & 31;
    const int cc = blockIdx.x >> 5;
    const int row0 = rb * 256 + w * 64;
    const int c0 = cc * 512;
    const char* fbase = (const char*)fbf;

    // A fragments: 4 row-frags x 8 k-steps, 16B/lane each, fully register-resident.
    v8bf a[4][8];
    #pragma unroll
    for (int mr = 0; mr < 4; ++mr) {
        const char* rp = fbase + (size_t)(row0 + mr * 16 + ll) * 512 + lh * 16;
        #pragma unroll
        for (int ks = 0; ks < 8; ++ks)
            a[mr][ks] = *reinterpret_cast<const v8bf*>(rp + ks * 64);
    }

    float se[4][4];
    #pragma unroll
    for (int mr = 0; mr < 4; ++mr)
        #pragma unroll
        for (int r = 0; r < 4; ++r) se[mr][r] = 0.f;

    const unsigned wbase = (unsigned)w * 4096u;
    char* lds0 = (char*)&Bsh[0][0];
    char* lds1 = (char*)&Bsh[1][0];

    // Stage 32 cols of f (as B rows) into LDS: linear LDS dest, pre-swizzled
    // global source so reads can use the XOR bank-swizzle (rule #21).
    auto stage = [&](int buf, int s) {
        char* lb = buf ? lds1 : lds0;
        #pragma unroll
        for (int t = 0; t < 4; ++t) {
            const unsigned o   = wbase + t * 1024u + (unsigned)l * 16u;
            const unsigned col = o >> 9;
            const unsigned kb  = o & 511u;
            const unsigned src = kb ^ ((col & 7u) << 4);
            const char* gp = fbase + (size_t)(c0 + s * 32 + (int)col) * 512 + src;
            __builtin_amdgcn_global_load_lds(
                (const __attribute__((address_space(1))) void*)gp,
                (__attribute__((address_space(3))) void*)(lb + wbase + t * 1024u),
                16, 0, 0);
        }
    };

    stage(0, 0);
    __syncthreads();

    for (int s = 0; s < 16; ++s) {
        if (s < 15) stage((s + 1) & 1, s + 1);
        const char* lb = (s & 1) ? lds1 : lds0;
        v4f acc[4][2];
        #pragma unroll
        for (int mr = 0; mr < 4; ++mr) {
            acc[mr][0] = (v4f){0.f, 0.f, 0.f, 0.f};
            acc[mr][1] = (v4f){0.f, 0.f, 0.f, 0.f};
        }
        #pragma unroll
        for (int ks = 0; ks < 8; ++ks) {
            const unsigned kb = (unsigned)(ks * 64 + lh * 16);
            const unsigned ad = (unsigned)ll * 512u + (kb ^ (((unsigned)ll & 7u) << 4));
            const v8bf b0 = *reinterpret_cast<const v8bf*>(lb + ad);
            const v8bf b1 = *reinterpret_cast<const v8bf*>(lb + ad + 8192);
            #pragma unroll
            for (int mr = 0; mr < 4; ++mr) {
                acc[mr][0] = __builtin_amdgcn_mfma_f32_16x16x32_bf16(a[mr][ks], b0, acc[mr][0], 0, 0, 0);
                acc[mr][1] = __builtin_amdgcn_mfma_f32_16x16x32_bf16(a[mr][ks], b1, acc[mr][1], 0, 0, 0);
            }
        }
        #pragma unroll
        for (int mr = 0; mr < 4; ++mr)
            #pragma unroll
            for (int nr = 0; nr < 2; ++nr)
                #pragma unroll
                for (int r = 0; r < 4; ++r)
                    se[mr][r] += __expf(acc[mr][nr][r] * INV_T);
        __syncthreads();
    }

    // Reduce over the 16 column-lanes (C/D layout: col = lane&15, row = (lane>>4)*4 + r).
    #pragma unroll
    for (int mr = 0; mr < 4; ++mr)
        #pragma unroll
        for (int r = 0; r < 4; ++r) {
            float v = se[mr][r];
            v += __shfl_xor(v, 1, 64);
            v += __shfl_xor(v, 2, 64);
            v += __shfl_xor(v, 4, 64);
            v += __shfl_xor(v, 8, 64);
            if (ll == 0)
                atomicAdd(&sumexp[row0 + mr * 16 + lh * 4 + r], v);
        }
}

// Per-row finalize: loss += log(sumexp - e^{1/T}) - (f_i.g - 1)/T / (cnt-1)
__global__ __launch_bounds__(256) void k_final(const unsigned short* __restrict__ fbf,
                                               const float* __restrict__ sumexp,
                                               const float* __restrict__ g,
                                               const int* __restrict__ cnt,
                                               const int* __restrict__ lab,
                                               float* __restrict__ out) {
    const int tid = threadIdx.x;
    const int w = tid >> 6, l = tid & 63;
    const int wid = blockIdx.x * 4 + w;
    const float expi = __expf(INV_T);
    float local = 0.f;
    for (int it = 0; it < 64; ++it) {
        const int row = wid * 64 + it;
        const int lb = lab[row];
        const uint2 u = *reinterpret_cast<const uint2*>((const char*)fbf + (size_t)row * 512 + l * 8);
        const float4 gv = *reinterpret_cast<const float4*>(g + lb * 256 + l * 4);
        const float f0 = __uint_as_float(u.x << 16);
        const float f1 = __uint_as_float(u.x & 0xffff0000u);
        const float f2 = __uint_as_float(u.y << 16);
        const float f3 = __uint_as_float(u.y & 0xffff0000u);
        float d = f0 * gv.x + f1 * gv.y + f2 * gv.z + f3 * gv.w;
        #pragma unroll
        for (int m = 1; m < 64; m <<= 1) d += __shfl_xor(d, m, 64);
        if (l == 0) {
            const int pc = cnt[lb] - 1;
            const float mp = (d - 1.0f) * INV_T / (float)(pc > 1 ? pc : 1);
            const float denom = sumexp[row] - expi;
            if (pc > 0) local += logf(denom) - mp;
        }
    }
    if (l == 0) atomicAdd(out, local);
}

extern "C" void kernel_launch(void* const* d_in, const int* in_sizes, int n_in,
                              void* d_out, int out_size, void* d_ws, size_t ws_size,
                              hipStream_t stream) {
    const float* feat = (const float*)d_in[0];
    const int* labels = (const int*)d_in[1];
    float* out = (float*)d_out;
    char* ws = (char*)d_ws;
    unsigned short* fbf = (unsigned short*)(ws + FBF_OFF);
    float* se = (float*)(ws + SE_OFF);
    float* g  = (float*)(ws + G_OFF);
    int* cnt  = (int*)(ws + CNT_OFF);

    k_zero<<<dim3(8), dim3(256), 0, stream>>>(se, g, cnt, out);
    k_norm<<<dim3(256), dim3(256), 0, stream>>>(feat, labels, fbf, g, cnt);
    k_score<<<dim3(512), dim3(256), 0, stream>>>(fbf, se);
    k_final<<<dim3(32), dim3(256), 0, stream>>>(fbf, se, g, cnt, labels, out);
}

// Round 2
// 77.644 us; speedup vs baseline: 1.3932x; 1.3932x over previous
//
#include <hip/hip_runtime.h>

typedef __bf16 v8bf __attribute__((ext_vector_type(8)));
typedef float v4f __attribute__((ext_vector_type(4)));

static constexpr int NR = 8192;
static constexpr int DD = 256;
static constexpr float INV_T = 1.0f / 0.3f;

// workspace layout (bytes)
static constexpr size_t FBF_OFF = 0;                    // 8192*256*2 = 4 MiB (bf16 normalized f)
static constexpr size_t SE_OFF  = 4194304;              // 8192 f32 (sum of exp per row)
static constexpr size_t G_OFF   = SE_OFF + 8192 * 4;    // 10*256 f32 class sums
static constexpr size_t CNT_OFF = G_OFF + 2560 * 4;     // 16 i32 class counts

__global__ __launch_bounds__(256) void k_zero(float* se, float* g, int* cnt, float* out) {
    const int i = blockIdx.x * 256 + threadIdx.x;
    for (int idx = i; idx < 8192; idx += gridDim.x * 256) se[idx] = 0.f;
    for (int idx = i; idx < 2560; idx += gridDim.x * 256) g[idx] = 0.f;
    if (i < 16) cnt[i] = 0;
    if (i == 0) out[0] = 0.f;
}

// L2-normalize rows -> bf16, accumulate class sums g[10][256] and counts.
__global__ __launch_bounds__(256) void k_norm(const float* __restrict__ x,
                                              const int* __restrict__ lab,
                                              unsigned short* __restrict__ fbf,
                                              float* __restrict__ g,
                                              int* __restrict__ cnt) {
    __shared__ float gsh[2560];
    __shared__ int csh[16];
    const int tid = threadIdx.x;
    const int w = tid >> 6, l = tid & 63;
    for (int i = tid; i < 2560; i += 256) gsh[i] = 0.f;
    if (tid < 16) csh[tid] = 0;
    __syncthreads();
    #pragma unroll
    for (int it = 0; it < 8; ++it) {
        const int row = blockIdx.x * 32 + it * 4 + w;
        const float4 v = *reinterpret_cast<const float4*>(x + row * DD + l * 4);
        float ss = v.x * v.x + v.y * v.y + v.z * v.z + v.w * v.w;
        #pragma unroll
        for (int m = 1; m < 64; m <<= 1) ss += __shfl_xor(ss, m, 64);
        const float rn = 1.0f / fmaxf(sqrtf(ss), 1e-12f);
        const float f0 = v.x * rn, f1 = v.y * rn, f2 = v.z * rn, f3 = v.w * rn;
        union { __bf16 h[4]; uint2 u; } pk;
        pk.h[0] = (__bf16)f0; pk.h[1] = (__bf16)f1;
        pk.h[2] = (__bf16)f2; pk.h[3] = (__bf16)f3;
        *reinterpret_cast<uint2*>(fbf + row * DD + l * 4) = pk.u;
        const int lb = lab[row];
        float* gb = &gsh[lb * DD + l * 4];
        atomicAdd(gb + 0, f0); atomicAdd(gb + 1, f1);
        atomicAdd(gb + 2, f2); atomicAdd(gb + 3, f3);
        if (l == 0) atomicAdd(&csh[lb], 1);
    }
    __syncthreads();
    for (int i = tid; i < 2560; i += 256) atomicAdd(&g[i], gsh[i]);
    if (tid < 10) atomicAdd(&cnt[tid], csh[tid]);
}

// Gram + exp row-sum kernel. Grid 512 = 32 row-blocks x 16 col-chunks.
// Block: 4 waves x 64 rows = 256 rows; col chunk = 512, staged 32 cols (16 KiB) at a time.
__global__ __launch_bounds__(256, 2) void k_score(const unsigned short* __restrict__ fbf,
                                                  float* __restrict__ sumexp) {
    __shared__ unsigned short Bsh[2][32 * 256];   // 2 x 16 KiB, double buffered
    const int tid = threadIdx.x;
    const int w = tid >> 6, l = tid & 63;
    const int ll = l & 15, lh = l >> 4;
    const int rb = blockIdx.x & 31;
    const int cc = blockIdx.x >> 5;
    const int row0 = rb * 256 + w * 64;
    const int c0 = cc * 512;
    const char* fbase = (const char*)fbf;

    // A fragments: 4 row-frags x 8 k-steps, 16B/lane each, fully register-resident.
    v8bf a[4][8];
    #pragma unroll
    for (int mr = 0; mr < 4; ++mr) {
        const char* rp = fbase + (size_t)(row0 + mr * 16 + ll) * 512 + lh * 16;
        #pragma unroll
        for (int ks = 0; ks < 8; ++ks)
            a[mr][ks] = *reinterpret_cast<const v8bf*>(rp + ks * 64);
    }

    float se[4][4];
    #pragma unroll
    for (int mr = 0; mr < 4; ++mr)
        #pragma unroll
        for (int r = 0; r < 4; ++r) se[mr][r] = 0.f;

    const unsigned wbase = (unsigned)w * 4096u;
    char* lds0 = (char*)&Bsh[0][0];
    char* lds1 = (char*)&Bsh[1][0];

    // Stage 32 cols of f (as B rows) into LDS: linear LDS dest, pre-swizzled
    // global source so reads can use the XOR bank-swizzle (rule #21).
    auto stage = [&](int buf, int s) {
        char* lb = buf ? lds1 : lds0;
        #pragma unroll
        for (int t = 0; t < 4; ++t) {
            const unsigned o   = wbase + t * 1024u + (unsigned)l * 16u;
            const unsigned col = o >> 9;
            const unsigned kb  = o & 511u;
            const unsigned src = kb ^ ((col & 7u) << 4);
            const char* gp = fbase + (size_t)(c0 + s * 32 + (int)col) * 512 + src;
            __builtin_amdgcn_global_load_lds(
                (const __attribute__((address_space(1))) void*)gp,
                (__attribute__((address_space(3))) void*)(lb + wbase + t * 1024u),
                16, 0, 0);
        }
    };

    stage(0, 0);
    __syncthreads();

    for (int s = 0; s < 16; ++s) {
        if (s < 15) stage((s + 1) & 1, s + 1);
        const char* lb = (s & 1) ? lds1 : lds0;
        v4f acc[4][2];
        #pragma unroll
        for (int mr = 0; mr < 4; ++mr) {
            acc[mr][0] = (v4f){0.f, 0.f, 0.f, 0.f};
            acc[mr][1] = (v4f){0.f, 0.f, 0.f, 0.f};
        }
        #pragma unroll
        for (int ks = 0; ks < 8; ++ks) {
            const unsigned kb = (unsigned)(ks * 64 + lh * 16);
            const unsigned ad = (unsigned)ll * 512u + (kb ^ (((unsigned)ll & 7u) << 4));
            const v8bf b0 = *reinterpret_cast<const v8bf*>(lb + ad);
            const v8bf b1 = *reinterpret_cast<const v8bf*>(lb + ad + 8192);
            #pragma unroll
            for (int mr = 0; mr < 4; ++mr) {
                acc[mr][0] = __builtin_amdgcn_mfma_f32_16x16x32_bf16(a[mr][ks], b0, acc[mr][0], 0, 0, 0);
                acc[mr][1] = __builtin_amdgcn_mfma_f32_16x16x32_bf16(a[mr][ks], b1, acc[mr][1], 0, 0, 0);
            }
        }
        #pragma unroll
        for (int mr = 0; mr < 4; ++mr)
            #pragma unroll
            for (int nr = 0; nr < 2; ++nr)
                #pragma unroll
                for (int r = 0; r < 4; ++r)
                    se[mr][r] += __expf(acc[mr][nr][r] * INV_T);
        __syncthreads();
    }

    // Reduce over the 16 column-lanes (C/D layout: col = lane&15, row = (lane>>4)*4 + r).
    #pragma unroll
    for (int mr = 0; mr < 4; ++mr)
        #pragma unroll
        for (int r = 0; r < 4; ++r) {
            float v = se[mr][r];
            v += __shfl_xor(v, 1, 64);
            v += __shfl_xor(v, 2, 64);
            v += __shfl_xor(v, 4, 64);
            v += __shfl_xor(v, 8, 64);
            if (ll == 0)
                atomicAdd(&sumexp[row0 + mr * 16 + lh * 4 + r], v);
        }
}

// Per-row finalize, one 16-lane group per row (16 rows/block, 512 blocks).
// loss_i = log(sumexp_i - e^{1/T}) - ((f_i.g_lb - 1)/T) / max(cnt-1,1), summed, negated at use.
__global__ __launch_bounds__(256) void k_final(const unsigned short* __restrict__ fbf,
                                               const float* __restrict__ sumexp,
                                               const float* __restrict__ g,
                                               const int* __restrict__ cnt,
                                               const int* __restrict__ lab,
                                               float* __restrict__ out) {
    __shared__ float lsum[16];
    const int tid = threadIdx.x;
    const int grp = tid >> 4, gl = tid & 15;
    const int row = blockIdx.x * 16 + grp;
    const int lb = lab[row];
    const char* rp = (const char*)fbf + (size_t)row * 512 + gl * 32;
    const uint4 u0 = *reinterpret_cast<const uint4*>(rp);
    const uint4 u1 = *reinterpret_cast<const uint4*>(rp + 16);
    const float* gp = g + lb * 256 + gl * 16;
    const float4 g0 = *reinterpret_cast<const float4*>(gp + 0);
    const float4 g1 = *reinterpret_cast<const float4*>(gp + 4);
    const float4 g2 = *reinterpret_cast<const float4*>(gp + 8);
    const float4 g3 = *reinterpret_cast<const float4*>(gp + 12);
    float d = 0.f;
    auto dot8 = [&](const uint4& u, const float4& a, const float4& b) {
        d += __uint_as_float(u.x << 16) * a.x + __uint_as_float(u.x & 0xffff0000u) * a.y
           + __uint_as_float(u.y << 16) * a.z + __uint_as_float(u.y & 0xffff0000u) * a.w
           + __uint_as_float(u.z << 16) * b.x + __uint_as_float(u.z & 0xffff0000u) * b.y
           + __uint_as_float(u.w << 16) * b.z + __uint_as_float(u.w & 0xffff0000u) * b.w;
    };
    dot8(u0, g0, g1);
    dot8(u1, g2, g3);
    d += __shfl_xor(d, 1, 64);
    d += __shfl_xor(d, 2, 64);
    d += __shfl_xor(d, 4, 64);
    d += __shfl_xor(d, 8, 64);
    if (gl == 0) {
        const int pc = cnt[lb] - 1;
        const float mp = (d - 1.0f) * INV_T / (float)(pc > 1 ? pc : 1);
        const float denom = sumexp[row] - __expf(INV_T);
        lsum[grp] = (pc > 0) ? (logf(denom) - mp) : 0.f;
    }
    __syncthreads();
    if (tid == 0) {
        float s = 0.f;
        #pragma unroll
        for (int i = 0; i < 16; ++i) s += lsum[i];
        atomicAdd(out, s);
    }
}

extern "C" void kernel_launch(void* const* d_in, const int* in_sizes, int n_in,
                              void* d_out, int out_size, void* d_ws, size_t ws_size,
                              hipStream_t stream) {
    const float* feat = (const float*)d_in[0];
    const int* labels = (const int*)d_in[1];
    float* out = (float*)d_out;
    char* ws = (char*)d_ws;
    unsigned short* fbf = (unsigned short*)(ws + FBF_OFF);
    float* se = (float*)(ws + SE_OFF);
    float* g  = (float*)(ws + G_OFF);
    int* cnt  = (int*)(ws + CNT_OFF);

    k_zero<<<dim3(8), dim3(256), 0, stream>>>(se, g, cnt, out);
    k_norm<<<dim3(256), dim3(256), 0, stream>>>(feat, labels, fbf, g, cnt);
    k_score<<<dim3(512), dim3(256), 0, stream>>>(fbf, se);
    k_final<<<dim3(512), dim3(256), 0, stream>>>(fbf, se, g, cnt, labels, out);
}